// Round 12
// baseline (131.963 us; speedup 1.0000x reference)
//
#include <hip/hip_runtime.h>
#include <hip/hip_bf16.h>
#include <stdint.h>

// Problem constants (B=2, T=2048, D=1024, H=16, DK=64)
#define Bc   2
#define Tc   2048
#define Dc   1024
#define Hc   16
#define DKc  64
#define BTc  4096
#define LOG2E 1.44269504088896f

typedef unsigned short u16;
typedef unsigned int u32;
typedef __attribute__((ext_vector_type(8))) short bf16x8;
typedef __attribute__((ext_vector_type(4))) float f32x4;
typedef __attribute__((ext_vector_type(2))) u32 u32x2;

static __device__ __forceinline__ u16 f2bf(float f) {
  union { float f; unsigned u; } v; v.f = f;
  unsigned r = v.u + 0x7fffu + ((v.u >> 16) & 1u);   // RNE
  return (u16)(r >> 16);
}

static __device__ __forceinline__ u32 cvt_pk_bf16(float lo, float hi) {
  u32 r;
  asm volatile("v_cvt_pk_bf16_f32 %0, %1, %2" : "=v"(r) : "v"(lo), "v"(hi));
  return r;
}

static __device__ __forceinline__ f32x4 mfma16(bf16x8 a, bf16x8 b, f32x4 c) {
  return __builtin_amdgcn_mfma_f32_16x16x32_bf16(a, b, c, 0, 0, 0);
}

// ------------- f32 -> bf16 conversion: one dispatch for all 7 tensors --------
__global__ void conv_kernel(const float* __restrict__ q, const float* __restrict__ k,
                            const float* __restrict__ v, const float* __restrict__ wq,
                            const float* __restrict__ wk, const float* __restrict__ wv,
                            const float* __restrict__ wo,
                            u16* __restrict__ Xq, u16* __restrict__ Xk, u16* __restrict__ Xv,
                            u16* __restrict__ Wq, u16* __restrict__ Wk, u16* __restrict__ Wv,
                            u16* __restrict__ Wo) {
  int z = blockIdx.z, bx = blockIdx.x;
  const float* src; u16* dst; int i;
  if (bx < 4096) {
    if (z == 3) return;
    src = z == 0 ? q : z == 1 ? k : v;
    dst = z == 0 ? Xq : z == 1 ? Xk : Xv;
    i = bx * 256 + threadIdx.x;
  } else {
    src = z == 0 ? wq : z == 1 ? wk : z == 2 ? wv : wo;
    dst = z == 0 ? Wq : z == 1 ? Wk : z == 2 ? Wv : Wo;
    i = (bx - 4096) * 256 + threadIdx.x;
  }
  float4 f = ((const float4*)src)[i];
  ushort4 r; r.x = f2bf(f.x); r.y = f2bf(f.y); r.z = f2bf(f.z); r.w = f2bf(f.w);
  ((ushort4*)dst)[i] = r;
}

#define AS1 const __attribute__((address_space(1))) void*
#define AS3 __attribute__((address_space(3))) void*

// ---------- fused Q/K/V projection (BM=64: 1536 blocks = 6/CU, dbuf) --------
// R12: port gemm_out's measured-faster BM=64 structure; barrier drains now
// covered by 6 co-resident blocks/CU instead of 3.
__global__ __launch_bounds__(256) void gemm_proj(const u16* __restrict__ Xq, const u16* __restrict__ Xk,
                                                 const u16* __restrict__ Xv, const u16* __restrict__ Wq,
                                                 const u16* __restrict__ Wk, const u16* __restrict__ Wv,
                                                 u16* __restrict__ Qh, u16* __restrict__ Kh,
                                                 u16* __restrict__ VTo) {
  __shared__ u16 As[2][64 * 32];
  __shared__ u16 Bs[2][128 * 32];
  int dd = blockIdx.x;
  int logical = (dd & 7) * 192 + (dd >> 3);   // bijective (1536 = 8*192)
  int mp = logical / 24, rest = logical % 24;
  int z = rest >> 3, ny = rest & 7;
  const u16* A = z == 0 ? Xq : z == 1 ? Xk : Xv;
  const u16* W = z == 0 ? Wq : z == 1 ? Wk : Wv;
  u16* outp    = z == 0 ? Qh : z == 1 ? Kh : VTo;
  float scale = (z == 0) ? 0.125f * LOG2E : 1.0f;   // fold 1/sqrt(DK)*log2e into Q
  int tid = threadIdx.x;
  int lane = tid & 63, wave = tid >> 6;
  int ln = lane & 15, g = lane >> 4;
  int m0 = mp * 64, n0 = ny * 128;
  int wm = (wave >> 1) * 32, wn = (wave & 1) * 64;
  f32x4 acc[2][4] = {};
  int ca = tid, cb0 = tid, cb1 = tid + 256;
  const u16* gA  = A + (size_t)(m0 + (ca  >> 2)) * 1024 + (ca  & 3) * 8;
  const u16* gW0 = W + (size_t)(n0 + (cb0 >> 2)) * 1024 + (cb0 & 3) * 8;
  const u16* gW1 = W + (size_t)(n0 + (cb1 >> 2)) * 1024 + (cb1 & 3) * 8;

#define PSTAGE(bufi, k0_) do {                                                                 \
    __builtin_amdgcn_global_load_lds((AS1)(gA  + (k0_)), (AS3)(&As[bufi][ca  * 8]), 16, 0, 0); \
    __builtin_amdgcn_global_load_lds((AS1)(gW0 + (k0_)), (AS3)(&Bs[bufi][cb0 * 8]), 16, 0, 0); \
    __builtin_amdgcn_global_load_lds((AS1)(gW1 + (k0_)), (AS3)(&Bs[bufi][cb1 * 8]), 16, 0, 0); \
  } while (0)

  PSTAGE(0, 0);
  __syncthreads();                     // tile 0 ready
  int cur = 0;
  for (int it = 0; it < 32; ++it) {
    if (it < 31) PSTAGE(cur ^ 1, (it + 1) * 32);   // issue NEXT before compute
    bf16x8 af[2], bfr[4];
#pragma unroll
    for (int mi = 0; mi < 2; ++mi) af[mi]  = *(const bf16x8*)&As[cur][(wm + mi * 16 + ln) * 32 + g * 8];
#pragma unroll
    for (int ni = 0; ni < 4; ++ni) bfr[ni] = *(const bf16x8*)&Bs[cur][(wn + ni * 16 + ln) * 32 + g * 8];
#pragma unroll
    for (int mi = 0; mi < 2; ++mi)
#pragma unroll
      for (int ni = 0; ni < 4; ++ni)
        acc[mi][ni] = mfma16(af[mi], bfr[ni], acc[mi][ni]);
    __syncthreads();                   // drains: next tile ready; cur free
    cur ^= 1;
  }
#undef PSTAGE

  if (z == 2) {
    // V^T [B,H,DK,T]: r-consecutive values are t-adjacent -> pack 4 into 8B
#pragma unroll
    for (int mi = 0; mi < 2; ++mi)
#pragma unroll
      for (int ni = 0; ni < 4; ++ni) {
        int t0 = m0 + wm + mi * 16 + g * 4;
        int gn = n0 + wn + ni * 16 + ln;
        size_t bhead = ((size_t)(t0 >> 11)) * Hc + (gn >> 6);
        ushort4 pk;
        pk.x = f2bf(acc[mi][ni][0]); pk.y = f2bf(acc[mi][ni][1]);
        pk.z = f2bf(acc[mi][ni][2]); pk.w = f2bf(acc[mi][ni][3]);
        *(ushort4*)&outp[(bhead * DKc + (gn & 63)) * Tc + (t0 & 2047)] = pk;
      }
  } else {
#pragma unroll
    for (int mi = 0; mi < 2; ++mi)
#pragma unroll
      for (int ni = 0; ni < 4; ++ni)
#pragma unroll
        for (int r = 0; r < 4; ++r) {
          int gm = m0 + wm + mi * 16 + g * 4 + r;
          int gn = n0 + wn + ni * 16 + ln;
          size_t bhead = ((size_t)(gm >> 11)) * Hc + (gn >> 6);
          outp[(bhead * Tc + (gm & 2047)) * DKc + (gn & 63)] = f2bf(acc[mi][ni][r] * scale);
        }
  }
}

// ---------- output projection + bias -> f32 (dbuf + XCD swizzle, BM=64) ------
__global__ __launch_bounds__(256) void gemm_out(const u16* __restrict__ Ain, const u16* __restrict__ W,
                                                float* __restrict__ of, const float* __restrict__ bias) {
  __shared__ u16 As[2][64 * 32];
  __shared__ u16 Bs[2][128 * 32];
  int dd = blockIdx.x;
  int logical = (dd & 7) * 64 + (dd >> 3);   // bijective (512 = 8*64)
  int mp = logical >> 3, ny = logical & 7;
  int tid = threadIdx.x;
  int lane = tid & 63, wave = tid >> 6;
  int ln = lane & 15, g = lane >> 4;
  int m0 = mp * 64, n0 = ny * 128;
  int wm = (wave >> 1) * 32, wn = (wave & 1) * 64;
  f32x4 acc[2][4] = {};
  int ca = tid, cb0 = tid, cb1 = tid + 256;
  const u16* gA  = Ain + (size_t)(m0 + (ca  >> 2)) * 1024 + (ca  & 3) * 8;
  const u16* gW0 = W   + (size_t)(n0 + (cb0 >> 2)) * 1024 + (cb0 & 3) * 8;
  const u16* gW1 = W   + (size_t)(n0 + (cb1 >> 2)) * 1024 + (cb1 & 3) * 8;

#define OSTAGE(bufi, k0_) do {                                                                 \
    __builtin_amdgcn_global_load_lds((AS1)(gA  + (k0_)), (AS3)(&As[bufi][ca  * 8]), 16, 0, 0); \
    __builtin_amdgcn_global_load_lds((AS1)(gW0 + (k0_)), (AS3)(&Bs[bufi][cb0 * 8]), 16, 0, 0); \
    __builtin_amdgcn_global_load_lds((AS1)(gW1 + (k0_)), (AS3)(&Bs[bufi][cb1 * 8]), 16, 0, 0); \
  } while (0)

  OSTAGE(0, 0);
  __syncthreads();
  int cur = 0;
  for (int it = 0; it < 32; ++it) {
    if (it < 31) OSTAGE(cur ^ 1, (it + 1) * 32);
    bf16x8 af[2], bfr[4];
#pragma unroll
    for (int mi = 0; mi < 2; ++mi) af[mi]  = *(const bf16x8*)&As[cur][(wm + mi * 16 + ln) * 32 + g * 8];
#pragma unroll
    for (int ni = 0; ni < 4; ++ni) bfr[ni] = *(const bf16x8*)&Bs[cur][(wn + ni * 16 + ln) * 32 + g * 8];
#pragma unroll
    for (int mi = 0; mi < 2; ++mi)
#pragma unroll
      for (int ni = 0; ni < 4; ++ni)
        acc[mi][ni] = mfma16(af[mi], bfr[ni], acc[mi][ni]);
    __syncthreads();
    cur ^= 1;
  }
#undef OSTAGE

#pragma unroll
  for (int mi = 0; mi < 2; ++mi)
#pragma unroll
    for (int ni = 0; ni < 4; ++ni)
#pragma unroll
      for (int r = 0; r < 4; ++r) {
        int gm = m0 + wm + mi * 16 + g * 4 + r;
        int gn = n0 + wn + ni * 16 + ln;
        of[(size_t)gm * 1024 + gn] = acc[mi][ni][r] + bias[gn];
      }
}

// -------- Flash attention: paired q-tiles + XCD-aware swizzle (unchanged) ----
__global__ __launch_bounds__(256, 2) void flash_attn(const u16* __restrict__ Qh,
                                                     const u16* __restrict__ Kh,
                                                     const u16* __restrict__ VT,
                                                     u16* __restrict__ O) {
  __shared__ u16 Ks[2][64 * 64];     // [kv_row][dk], XOR-swizzled (byte^=(row&7)<<4)
  __shared__ u16 Vs[2][64 * 64];     // [dk][t_off], XOR-swizzled
  __shared__ u16 P_lds[8][16][64];   // [tile*4+wave][q][k], XOR-swizzled
  int d = blockIdx.x;
  int logical = (d & 7) * 64 + (d >> 3);   // bijective XCD chunking (nwg=512)
  int bh = logical >> 4, pid = logical & 15;
  int qhi = 16 + pid, qlo = 15 - pid;
  int b = bh >> 4, h = bh & (Hc - 1);
  int tid = threadIdx.x, wave = tid >> 6, lane = tid & 63;
  int ln = lane & 15, g = lane >> 4;
  float slope2 = exp2f(-0.5f * (float)(h + 1)) * LOG2E;   // slope_h * log2(e)

  const u16* gK = Kh + (size_t)bh * Tc * DKc;
  const u16* gV = VT + (size_t)bh * DKc * Tc;
  // staging: pre-swizzled global source + linear LDS dest (rule #21)
  int c0 = tid, c1 = tid + 256;
  int r0 = c0 >> 3, r1 = c1 >> 3;
  int e0 = ((c0 & 7) << 3) ^ ((r0 & 7) << 3);
  int e1 = ((c1 & 7) << 3) ^ ((r1 & 7) << 3);
  size_t kO0 = (size_t)r0 * DKc + e0, kO1 = (size_t)r1 * DKc + e1;
  size_t vO0 = (size_t)r0 * Tc + e0, vO1 = (size_t)r1 * Tc + e1;

#define STAGE(bufi, ks_) do {                                                                  \
    __builtin_amdgcn_global_load_lds((AS1)(gK + (size_t)(ks_) * DKc + kO0),                    \
                                     (AS3)(&Ks[bufi][c0 * 8]), 16, 0, 0);                      \
    __builtin_amdgcn_global_load_lds((AS1)(gK + (size_t)(ks_) * DKc + kO1),                    \
                                     (AS3)(&Ks[bufi][c1 * 8]), 16, 0, 0);                      \
    __builtin_amdgcn_global_load_lds((AS1)(gV + (size_t)(ks_) + vO0),                          \
                                     (AS3)(&Vs[bufi][c0 * 8]), 16, 0, 0);                      \
    __builtin_amdgcn_global_load_lds((AS1)(gV + (size_t)(ks_) + vO1),                          \
                                     (AS3)(&Vs[bufi][c1 * 8]), 16, 0, 0);                      \
  } while (0)

  int qlocal = wave * 16 + ln;       // lane's q-row within a 64-row tile
  int qgH = qhi * 64 + qlocal, qgL = qlo * 64 + qlocal;
  const u16* QpH = Qh + ((size_t)bh * Tc + qgH) * DKc;
  const u16* QpL = Qh + ((size_t)bh * Tc + qgL) * DKc;
  bf16x8 qfH0 = *(const bf16x8*)&QpH[g * 8];
  bf16x8 qfH1 = *(const bf16x8*)&QpH[32 + g * 8];
  bf16x8 qfL0 = *(const bf16x8*)&QpL[g * 8];
  bf16x8 qfL1 = *(const bf16x8*)&QpL[32 + g * 8];

  // per-lane ALiBi offsets for the k's this lane owns: k_local = j*16+g*4+r
  float vb[4][4];
#pragma unroll
  for (int j = 0; j < 4; ++j)
#pragma unroll
    for (int r = 0; r < 4; ++r)
      vb[j][r] = slope2 * (float)(j * 16 + g * 4 + r);

  f32x4 accH[4] = {}, accL[4] = {};
  float MH = -1e30f, LH = 0.f, ML = -1e30f, LL = 0.f;

  // one tile-step: QK^T (swapped), softmax (defer-max), PV accumulate
  auto tile_step = [&](int buf, int ks, bool diag, bf16x8 qf0, bf16x8 qf1,
                       int qg, float& Mx, float& Lx, f32x4* accO, int pslot) {
    f32x4 s[4] = {};
    __builtin_amdgcn_s_setprio(1);
#pragma unroll
    for (int j = 0; j < 4; ++j) {
      int row = j * 16 + ln, sw = (row & 7) << 3;
      bf16x8 kf0 = *(const bf16x8*)&Ks[buf][row * DKc + ((g * 8) ^ sw)];
      bf16x8 kf1 = *(const bf16x8*)&Ks[buf][row * DKc + ((32 + g * 8) ^ sw)];
      s[j] = mfma16(kf0, qf0, s[j]);
      s[j] = mfma16(kf1, qf1, s[j]);
    }
    __builtin_amdgcn_s_setprio(0);
    float vv[4][4];
    float mloc = -1e30f;
#pragma unroll
    for (int j = 0; j < 4; ++j)
#pragma unroll
      for (int r = 0; r < 4; ++r) {
        float t = s[j][r] + vb[j][r];
        if (diag) t = (j * 16 + g * 4 + r > qlocal) ? -1e30f : t;
        vv[j][r] = t;
        mloc = fmaxf(mloc, t);
      }
    mloc = fmaxf(mloc, __shfl_xor(mloc, 16, 64));
    mloc = fmaxf(mloc, __shfl_xor(mloc, 32, 64));
    float cterm = slope2 * (float)(ks - qg);   // true score = vv + cterm
    float mc = mloc + cterm;
    if (__any(mc > Mx)) {                      // rescale only when max grows (rare)
      float newM = fmaxf(Mx, mc);
      float sc = __builtin_amdgcn_exp2f(Mx - newM);
      Mx = newM;
      Lx *= sc;
      float scb[4];
#pragma unroll
      for (int r = 0; r < 4; ++r) scb[r] = __shfl(sc, g * 4 + r, 64);
#pragma unroll
      for (int nd = 0; nd < 4; ++nd)
#pragma unroll
        for (int r = 0; r < 4; ++r) accO[nd][r] *= scb[r];
    }
    float dsub = Mx - cterm;
    float rs = 0.f;
#pragma unroll
    for (int j = 0; j < 4; ++j)
#pragma unroll
      for (int r = 0; r < 4; ++r) {
        float p = __builtin_amdgcn_exp2f(vv[j][r] - dsub);
        vv[j][r] = p;
        rs += p;
      }
    Lx += rs;                          // cross-g reduce deferred to epilogue
    char* Prow = (char*)&P_lds[pslot][ln][0];
    int psw = (ln & 7) << 4;
#pragma unroll
    for (int j = 0; j < 4; ++j) {
      u32x2 w;
      w.x = cvt_pk_bf16(vv[j][0], vv[j][1]);
      w.y = cvt_pk_bf16(vv[j][2], vv[j][3]);
      *(u32x2*)(Prow + ((j * 32 + g * 8) ^ psw)) = w;
    }
    __builtin_amdgcn_s_setprio(1);
#pragma unroll
    for (int kk = 0; kk < 2; ++kk) {
      bf16x8 pa = *(const bf16x8*)(Prow + ((kk * 64 + g * 16) ^ psw));
#pragma unroll
      for (int nd = 0; nd < 4; ++nd) {
        int d2 = nd * 16 + ln, o = kk * 32 + g * 8;
        bf16x8 vf = *(const bf16x8*)&Vs[buf][d2 * DKc + (o ^ ((d2 & 7) << 3))];
        accO[nd] = mfma16(pa, vf, accO[nd]);
      }
    }
    __builtin_amdgcn_s_setprio(0);
  };

  STAGE(0, qhi * 64);                // hi diagonal tile first
  __syncthreads();
  int buf = 0;
  for (int kb = qhi; kb >= 0; --kb) {
    int ks = kb * 64;
    if (kb > 0) STAGE(buf ^ 1, ks - 64);   // prefetch (descending) under compute
    tile_step(buf, ks, kb == qhi, qfH0, qfH1, qgH, MH, LH, accH, wave);
    if (kb <= qlo)
      tile_step(buf, ks, kb == qlo, qfL0, qfL1, qgL, ML, LL, accL, wave + 4);
    __syncthreads();                 // next tile staged; buf free
    buf ^= 1;
  }

  // ---- epilogue: finish L reduce, O /= L, write [B,T,D] bf16 (both tiles) ----
#pragma unroll
  for (int tile = 0; tile < 2; ++tile) {
    float Lx = tile ? LL : LH;
    f32x4* accO = tile ? accL : accH;
    int qb = tile ? qlo : qhi;
    float Lf = Lx + __shfl_xor(Lx, 16, 64);
    Lf = Lf + __shfl_xor(Lf, 32, 64);
    float linv[4];
#pragma unroll
    for (int r = 0; r < 4; ++r) linv[r] = 1.0f / __shfl(Lf, g * 4 + r, 64);
#pragma unroll
    for (int nd = 0; nd < 4; ++nd)
#pragma unroll
      for (int r = 0; r < 4; ++r) {
        int t = qb * 64 + wave * 16 + g * 4 + r;
        int dcol = h * 64 + nd * 16 + ln;
        O[((size_t)(b * Tc + t)) * Dc + dcol] = f2bf(accO[nd][r] * linv[r]);
      }
  }
#undef STAGE
}

// -----------------------------------------------------------------------------
extern "C" void kernel_launch(void* const* d_in, const int* in_sizes, int n_in,
                              void* d_out, int out_size, void* d_ws, size_t ws_size,
                              hipStream_t stream) {
  const float* q  = (const float*)d_in[0];
  const float* k  = (const float*)d_in[1];
  const float* v  = (const float*)d_in[2];
  // d_in[3] = alibi_bias [H,T,T] — intentionally unused (computed on the fly)
  const float* wq = (const float*)d_in[4];
  const float* wk = (const float*)d_in[5];
  const float* wv = (const float*)d_in[6];
  const float* wo = (const float*)d_in[7];
  const float* bo = (const float*)d_in[8];

  char* ws = (char*)d_ws;
  const size_t MB = 1024 * 1024;
  u16* Xq = (u16*)(ws + 0 * MB);    // [4096,1024] bf16
  u16* Xk = (u16*)(ws + 8 * MB);
  u16* Xv = (u16*)(ws + 16 * MB);
  u16* Wq = (u16*)(ws + 24 * MB);   // [1024,1024] bf16
  u16* Wk = (u16*)(ws + 26 * MB);
  u16* Wv = (u16*)(ws + 28 * MB);
  u16* Wo = (u16*)(ws + 30 * MB);
  u16* Qh = (u16*)(ws + 32 * MB);   // [B,H,T,DK] bf16
  u16* Kh = (u16*)(ws + 40 * MB);   // [B,H,T,DK]
  u16* VT = (u16*)(ws + 48 * MB);   // [B,H,DK,T]
  u16* Ob = (u16*)(ws + 56 * MB);   // [B,T,D]
  float* out = (float*)d_out;

  // f32 -> bf16 (single dispatch: X's + W's)
  conv_kernel<<<dim3(4096 + 1024, 1, 4), 256, 0, stream>>>(q, k, v, wq, wk, wv, wo,
                                                           Xq, Xk, Xv, Wq, Wk, Wv, Wo);
  // fused Q/K/V projections (BM=64: 1536 blocks = 6/CU, XCD swizzle)
  gemm_proj<<<dim3(1536), 256, 0, stream>>>(Xq, Xk, Xv, Wq, Wk, Wv, Qh, Kh, VT);
  // attention (paired q-tiles + XCD swizzle: 512 blocks, balanced)
  flash_attn<<<dim3(512), 256, 0, stream>>>(Qh, Kh, VT, Ob);
  // output projection + bias -> f32 d_out (512 blocks, XCD swizzle)
  gemm_out<<<dim3(512), 256, 0, stream>>>(Ob, Wo, out, bo);
}

// Round 13
// 116.785 us; speedup vs baseline: 1.1300x; 1.1300x over previous
//
#include <hip/hip_runtime.h>
#include <hip/hip_bf16.h>
#include <stdint.h>

// Problem constants (B=2, T=2048, D=1024, H=16, DK=64)
#define Bc   2
#define Tc   2048
#define Dc   1024
#define Hc   16
#define DKc  64
#define BTc  4096
#define LOG2E 1.44269504088896f

typedef unsigned short u16;
typedef unsigned int u32;
typedef __attribute__((ext_vector_type(8))) short bf16x8;
typedef __attribute__((ext_vector_type(4))) float f32x4;
typedef __attribute__((ext_vector_type(2))) u32 u32x2;

static __device__ __forceinline__ u16 f2bf(float f) {
  union { float f; unsigned u; } v; v.f = f;
  unsigned r = v.u + 0x7fffu + ((v.u >> 16) & 1u);   // RNE
  return (u16)(r >> 16);
}

static __device__ __forceinline__ u32 cvt_pk_bf16(float lo, float hi) {
  u32 r;
  asm volatile("v_cvt_pk_bf16_f32 %0, %1, %2" : "=v"(r) : "v"(lo), "v"(hi));
  return r;
}

static __device__ __forceinline__ f32x4 mfma16(bf16x8 a, bf16x8 b, f32x4 c) {
  return __builtin_amdgcn_mfma_f32_16x16x32_bf16(a, b, c, 0, 0, 0);
}

// ------------- f32 -> bf16 conversion (packed grid: zero wasted blocks) ------
// grid (4096,1,4): z<3 -> X[z] (4096 blocks each); z==3 -> all 4 W's (bx>>10).
__global__ void conv_kernel(const float* __restrict__ q, const float* __restrict__ k,
                            const float* __restrict__ v, const float* __restrict__ wq,
                            const float* __restrict__ wk, const float* __restrict__ wv,
                            const float* __restrict__ wo,
                            u16* __restrict__ Xq, u16* __restrict__ Xk, u16* __restrict__ Xv,
                            u16* __restrict__ Wq, u16* __restrict__ Wk, u16* __restrict__ Wv,
                            u16* __restrict__ Wo) {
  int z = blockIdx.z, bx = blockIdx.x;
  const float* src; u16* dst; int i;
  if (z < 3) {
    src = z == 0 ? q : z == 1 ? k : v;
    dst = z == 0 ? Xq : z == 1 ? Xk : Xv;
    i = bx * 256 + threadIdx.x;
  } else {
    int w = bx >> 10;
    src = w == 0 ? wq : w == 1 ? wk : w == 2 ? wv : wo;
    dst = w == 0 ? Wq : w == 1 ? Wk : w == 2 ? Wv : Wo;
    i = (bx & 1023) * 256 + threadIdx.x;
  }
  float4 f = ((const float4*)src)[i];
  ushort4 r; r.x = f2bf(f.x); r.y = f2bf(f.y); r.z = f2bf(f.z); r.w = f2bf(f.w);
  ((ushort4*)dst)[i] = r;
}

#define AS1 const __attribute__((address_space(1))) void*
#define AS3 __attribute__((address_space(3))) void*

// ---------- fused Q/K/V projection (R11: BM=128, dbuf, XCD swizzle) ----------
__global__ __launch_bounds__(256) void gemm_proj(const u16* __restrict__ Xq, const u16* __restrict__ Xk,
                                                 const u16* __restrict__ Xv, const u16* __restrict__ Wq,
                                                 const u16* __restrict__ Wk, const u16* __restrict__ Wv,
                                                 u16* __restrict__ Qh, u16* __restrict__ Kh,
                                                 u16* __restrict__ VTo) {
  __shared__ u16 As[2][128 * 32];
  __shared__ u16 Bs[2][128 * 32];
  int dd = blockIdx.x;
  int logical = (dd & 7) * 96 + (dd >> 3);   // bijective (768 = 8*96)
  int mp = logical / 24, rest = logical % 24;
  int z = rest >> 3, ny = rest & 7;
  const u16* A = z == 0 ? Xq : z == 1 ? Xk : Xv;
  const u16* W = z == 0 ? Wq : z == 1 ? Wk : Wv;
  u16* outp    = z == 0 ? Qh : z == 1 ? Kh : VTo;
  float scale = (z == 0) ? 0.125f * LOG2E : 1.0f;   // fold 1/sqrt(DK)*log2e into Q
  int tid = threadIdx.x;
  int lane = tid & 63, wave = tid >> 6;
  int ln = lane & 15, g = lane >> 4;
  int m0 = mp * 128, n0 = ny * 128;
  int wm = (wave >> 1) * 64, wn = (wave & 1) * 64;
  f32x4 acc[4][4] = {};
  int c0 = tid, c1 = tid + 256;
  const u16* gA0 = A + (size_t)(m0 + (c0 >> 2)) * 1024 + (c0 & 3) * 8;
  const u16* gA1 = A + (size_t)(m0 + (c1 >> 2)) * 1024 + (c1 & 3) * 8;
  const u16* gW0 = W + (size_t)(n0 + (c0 >> 2)) * 1024 + (c0 & 3) * 8;
  const u16* gW1 = W + (size_t)(n0 + (c1 >> 2)) * 1024 + (c1 & 3) * 8;

#define PSTAGE(bufi, k0_) do {                                                                 \
    __builtin_amdgcn_global_load_lds((AS1)(gA0 + (k0_)), (AS3)(&As[bufi][c0 * 8]), 16, 0, 0);  \
    __builtin_amdgcn_global_load_lds((AS1)(gA1 + (k0_)), (AS3)(&As[bufi][c1 * 8]), 16, 0, 0);  \
    __builtin_amdgcn_global_load_lds((AS1)(gW0 + (k0_)), (AS3)(&Bs[bufi][c0 * 8]), 16, 0, 0);  \
    __builtin_amdgcn_global_load_lds((AS1)(gW1 + (k0_)), (AS3)(&Bs[bufi][c1 * 8]), 16, 0, 0);  \
  } while (0)

  PSTAGE(0, 0);
  __syncthreads();                     // tile 0 ready
  int cur = 0;
  for (int it = 0; it < 32; ++it) {
    if (it < 31) PSTAGE(cur ^ 1, (it + 1) * 32);   // issue NEXT before compute
    bf16x8 af[4], bfr[4];
#pragma unroll
    for (int mi = 0; mi < 4; ++mi) af[mi]  = *(const bf16x8*)&As[cur][(wm + mi * 16 + ln) * 32 + g * 8];
#pragma unroll
    for (int ni = 0; ni < 4; ++ni) bfr[ni] = *(const bf16x8*)&Bs[cur][(wn + ni * 16 + ln) * 32 + g * 8];
#pragma unroll
    for (int mi = 0; mi < 4; ++mi)
#pragma unroll
      for (int ni = 0; ni < 4; ++ni)
        acc[mi][ni] = mfma16(af[mi], bfr[ni], acc[mi][ni]);
    __syncthreads();                   // drains: next tile ready; cur free for it+1
    cur ^= 1;
  }
#undef PSTAGE

  if (z == 2) {
    // V^T [B,H,DK,T]: r-consecutive values are t-adjacent -> pack 4 into 8B
#pragma unroll
    for (int mi = 0; mi < 4; ++mi)
#pragma unroll
      for (int ni = 0; ni < 4; ++ni) {
        int t0 = m0 + wm + mi * 16 + g * 4;
        int gn = n0 + wn + ni * 16 + ln;
        size_t bhead = ((size_t)(t0 >> 11)) * Hc + (gn >> 6);
        ushort4 pk;
        pk.x = f2bf(acc[mi][ni][0]); pk.y = f2bf(acc[mi][ni][1]);
        pk.z = f2bf(acc[mi][ni][2]); pk.w = f2bf(acc[mi][ni][3]);
        *(ushort4*)&outp[(bhead * DKc + (gn & 63)) * Tc + (t0 & 2047)] = pk;
      }
  } else {
#pragma unroll
    for (int mi = 0; mi < 4; ++mi)
#pragma unroll
      for (int ni = 0; ni < 4; ++ni)
#pragma unroll
        for (int r = 0; r < 4; ++r) {
          int gm = m0 + wm + mi * 16 + g * 4 + r;
          int gn = n0 + wn + ni * 16 + ln;
          size_t bhead = ((size_t)(gm >> 11)) * Hc + (gn >> 6);
          outp[(bhead * Tc + (gm & 2047)) * DKc + (gn & 63)] = f2bf(acc[mi][ni][r] * scale);
        }
  }
}

// ---------- output projection + bias -> f32 (dbuf + XCD swizzle, BM=64) ------
__global__ __launch_bounds__(256) void gemm_out(const u16* __restrict__ Ain, const u16* __restrict__ W,
                                                float* __restrict__ of, const float* __restrict__ bias) {
  __shared__ u16 As[2][64 * 32];
  __shared__ u16 Bs[2][128 * 32];
  int dd = blockIdx.x;
  int logical = (dd & 7) * 64 + (dd >> 3);   // bijective (512 = 8*64)
  int mp = logical >> 3, ny = logical & 7;
  int tid = threadIdx.x;
  int lane = tid & 63, wave = tid >> 6;
  int ln = lane & 15, g = lane >> 4;
  int m0 = mp * 64, n0 = ny * 128;
  int wm = (wave >> 1) * 32, wn = (wave & 1) * 64;
  f32x4 acc[2][4] = {};
  int ca = tid, cb0 = tid, cb1 = tid + 256;
  const u16* gA  = Ain + (size_t)(m0 + (ca  >> 2)) * 1024 + (ca  & 3) * 8;
  const u16* gW0 = W   + (size_t)(n0 + (cb0 >> 2)) * 1024 + (cb0 & 3) * 8;
  const u16* gW1 = W   + (size_t)(n0 + (cb1 >> 2)) * 1024 + (cb1 & 3) * 8;

#define OSTAGE(bufi, k0_) do {                                                                 \
    __builtin_amdgcn_global_load_lds((AS1)(gA  + (k0_)), (AS3)(&As[bufi][ca  * 8]), 16, 0, 0); \
    __builtin_amdgcn_global_load_lds((AS1)(gW0 + (k0_)), (AS3)(&Bs[bufi][cb0 * 8]), 16, 0, 0); \
    __builtin_amdgcn_global_load_lds((AS1)(gW1 + (k0_)), (AS3)(&Bs[bufi][cb1 * 8]), 16, 0, 0); \
  } while (0)

  OSTAGE(0, 0);
  __syncthreads();
  int cur = 0;
  for (int it = 0; it < 32; ++it) {
    if (it < 31) OSTAGE(cur ^ 1, (it + 1) * 32);
    bf16x8 af[2], bfr[4];
#pragma unroll
    for (int mi = 0; mi < 2; ++mi) af[mi]  = *(const bf16x8*)&As[cur][(wm + mi * 16 + ln) * 32 + g * 8];
#pragma unroll
    for (int ni = 0; ni < 4; ++ni) bfr[ni] = *(const bf16x8*)&Bs[cur][(wn + ni * 16 + ln) * 32 + g * 8];
#pragma unroll
    for (int mi = 0; mi < 2; ++mi)
#pragma unroll
      for (int ni = 0; ni < 4; ++ni)
        acc[mi][ni] = mfma16(af[mi], bfr[ni], acc[mi][ni]);
    __syncthreads();
    cur ^= 1;
  }
#undef OSTAGE

#pragma unroll
  for (int mi = 0; mi < 2; ++mi)
#pragma unroll
    for (int ni = 0; ni < 4; ++ni)
#pragma unroll
      for (int r = 0; r < 4; ++r) {
        int gm = m0 + wm + mi * 16 + g * 4 + r;
        int gn = n0 + wn + ni * 16 + ln;
        of[(size_t)gm * 1024 + gn] = acc[mi][ni][r] + bias[gn];
      }
}

// -------- Flash attention: paired q-tiles + XCD-aware swizzle (unchanged) ----
__global__ __launch_bounds__(256, 2) void flash_attn(const u16* __restrict__ Qh,
                                                     const u16* __restrict__ Kh,
                                                     const u16* __restrict__ VT,
                                                     u16* __restrict__ O) {
  __shared__ u16 Ks[2][64 * 64];     // [kv_row][dk], XOR-swizzled (byte^=(row&7)<<4)
  __shared__ u16 Vs[2][64 * 64];     // [dk][t_off], XOR-swizzled
  __shared__ u16 P_lds[8][16][64];   // [tile*4+wave][q][k], XOR-swizzled
  int d = blockIdx.x;
  int logical = (d & 7) * 64 + (d >> 3);   // bijective XCD chunking (nwg=512)
  int bh = logical >> 4, pid = logical & 15;
  int qhi = 16 + pid, qlo = 15 - pid;
  int b = bh >> 4, h = bh & (Hc - 1);
  int tid = threadIdx.x, wave = tid >> 6, lane = tid & 63;
  int ln = lane & 15, g = lane >> 4;
  float slope2 = exp2f(-0.5f * (float)(h + 1)) * LOG2E;   // slope_h * log2(e)

  const u16* gK = Kh + (size_t)bh * Tc * DKc;
  const u16* gV = VT + (size_t)bh * DKc * Tc;
  // staging: pre-swizzled global source + linear LDS dest (rule #21)
  int c0 = tid, c1 = tid + 256;
  int r0 = c0 >> 3, r1 = c1 >> 3;
  int e0 = ((c0 & 7) << 3) ^ ((r0 & 7) << 3);
  int e1 = ((c1 & 7) << 3) ^ ((r1 & 7) << 3);
  size_t kO0 = (size_t)r0 * DKc + e0, kO1 = (size_t)r1 * DKc + e1;
  size_t vO0 = (size_t)r0 * Tc + e0, vO1 = (size_t)r1 * Tc + e1;

#define STAGE(bufi, ks_) do {                                                                  \
    __builtin_amdgcn_global_load_lds((AS1)(gK + (size_t)(ks_) * DKc + kO0),                    \
                                     (AS3)(&Ks[bufi][c0 * 8]), 16, 0, 0);                      \
    __builtin_amdgcn_global_load_lds((AS1)(gK + (size_t)(ks_) * DKc + kO1),                    \
                                     (AS3)(&Ks[bufi][c1 * 8]), 16, 0, 0);                      \
    __builtin_amdgcn_global_load_lds((AS1)(gV + (size_t)(ks_) + vO0),                          \
                                     (AS3)(&Vs[bufi][c0 * 8]), 16, 0, 0);                      \
    __builtin_amdgcn_global_load_lds((AS1)(gV + (size_t)(ks_) + vO1),                          \
                                     (AS3)(&Vs[bufi][c1 * 8]), 16, 0, 0);                      \
  } while (0)

  int qlocal = wave * 16 + ln;       // lane's q-row within a 64-row tile
  int qgH = qhi * 64 + qlocal, qgL = qlo * 64 + qlocal;
  const u16* QpH = Qh + ((size_t)bh * Tc + qgH) * DKc;
  const u16* QpL = Qh + ((size_t)bh * Tc + qgL) * DKc;
  bf16x8 qfH0 = *(const bf16x8*)&QpH[g * 8];
  bf16x8 qfH1 = *(const bf16x8*)&QpH[32 + g * 8];
  bf16x8 qfL0 = *(const bf16x8*)&QpL[g * 8];
  bf16x8 qfL1 = *(const bf16x8*)&QpL[32 + g * 8];

  // per-lane ALiBi offsets for the k's this lane owns: k_local = j*16+g*4+r
  float vb[4][4];
#pragma unroll
  for (int j = 0; j < 4; ++j)
#pragma unroll
    for (int r = 0; r < 4; ++r)
      vb[j][r] = slope2 * (float)(j * 16 + g * 4 + r);

  f32x4 accH[4] = {}, accL[4] = {};
  float MH = -1e30f, LH = 0.f, ML = -1e30f, LL = 0.f;

  // one tile-step: QK^T (swapped), softmax (defer-max), PV accumulate
  auto tile_step = [&](int buf, int ks, bool diag, bf16x8 qf0, bf16x8 qf1,
                       int qg, float& Mx, float& Lx, f32x4* accO, int pslot) {
    f32x4 s[4] = {};
    __builtin_amdgcn_s_setprio(1);
#pragma unroll
    for (int j = 0; j < 4; ++j) {
      int row = j * 16 + ln, sw = (row & 7) << 3;
      bf16x8 kf0 = *(const bf16x8*)&Ks[buf][row * DKc + ((g * 8) ^ sw)];
      bf16x8 kf1 = *(const bf16x8*)&Ks[buf][row * DKc + ((32 + g * 8) ^ sw)];
      s[j] = mfma16(kf0, qf0, s[j]);
      s[j] = mfma16(kf1, qf1, s[j]);
    }
    __builtin_amdgcn_s_setprio(0);
    float vv[4][4];
    float mloc = -1e30f;
#pragma unroll
    for (int j = 0; j < 4; ++j)
#pragma unroll
      for (int r = 0; r < 4; ++r) {
        float t = s[j][r] + vb[j][r];
        if (diag) t = (j * 16 + g * 4 + r > qlocal) ? -1e30f : t;
        vv[j][r] = t;
        mloc = fmaxf(mloc, t);
      }
    mloc = fmaxf(mloc, __shfl_xor(mloc, 16, 64));
    mloc = fmaxf(mloc, __shfl_xor(mloc, 32, 64));
    float cterm = slope2 * (float)(ks - qg);   // true score = vv + cterm
    float mc = mloc + cterm;
    if (__any(mc > Mx)) {                      // rescale only when max grows (rare)
      float newM = fmaxf(Mx, mc);
      float sc = __builtin_amdgcn_exp2f(Mx - newM);
      Mx = newM;
      Lx *= sc;
      float scb[4];
#pragma unroll
      for (int r = 0; r < 4; ++r) scb[r] = __shfl(sc, g * 4 + r, 64);
#pragma unroll
      for (int nd = 0; nd < 4; ++nd)
#pragma unroll
        for (int r = 0; r < 4; ++r) accO[nd][r] *= scb[r];
    }
    float dsub = Mx - cterm;
    float rs = 0.f;
#pragma unroll
    for (int j = 0; j < 4; ++j)
#pragma unroll
      for (int r = 0; r < 4; ++r) {
        float p = __builtin_amdgcn_exp2f(vv[j][r] - dsub);
        vv[j][r] = p;
        rs += p;
      }
    Lx += rs;                          // cross-g reduce deferred to epilogue
    char* Prow = (char*)&P_lds[pslot][ln][0];
    int psw = (ln & 7) << 4;
#pragma unroll
    for (int j = 0; j < 4; ++j) {
      u32x2 w;
      w.x = cvt_pk_bf16(vv[j][0], vv[j][1]);
      w.y = cvt_pk_bf16(vv[j][2], vv[j][3]);
      *(u32x2*)(Prow + ((j * 32 + g * 8) ^ psw)) = w;
    }
    __builtin_amdgcn_s_setprio(1);
#pragma unroll
    for (int kk = 0; kk < 2; ++kk) {
      bf16x8 pa = *(const bf16x8*)(Prow + ((kk * 64 + g * 16) ^ psw));
#pragma unroll
      for (int nd = 0; nd < 4; ++nd) {
        int d2 = nd * 16 + ln, o = kk * 32 + g * 8;
        bf16x8 vf = *(const bf16x8*)&Vs[buf][d2 * DKc + (o ^ ((d2 & 7) << 3))];
        accO[nd] = mfma16(pa, vf, accO[nd]);
      }
    }
    __builtin_amdgcn_s_setprio(0);
  };

  STAGE(0, qhi * 64);                // hi diagonal tile first
  __syncthreads();
  int buf = 0;
  for (int kb = qhi; kb >= 0; --kb) {
    int ks = kb * 64;
    if (kb > 0) STAGE(buf ^ 1, ks - 64);   // prefetch (descending) under compute
    tile_step(buf, ks, kb == qhi, qfH0, qfH1, qgH, MH, LH, accH, wave);
    if (kb <= qlo)
      tile_step(buf, ks, kb == qlo, qfL0, qfL1, qgL, ML, LL, accL, wave + 4);
    __syncthreads();                 // next tile staged; buf free
    buf ^= 1;
  }

  // ---- epilogue: finish L reduce, O /= L, write [B,T,D] bf16 (both tiles) ----
#pragma unroll
  for (int tile = 0; tile < 2; ++tile) {
    float Lx = tile ? LL : LH;
    f32x4* accO = tile ? accL : accH;
    int qb = tile ? qlo : qhi;
    float Lf = Lx + __shfl_xor(Lx, 16, 64);
    Lf = Lf + __shfl_xor(Lf, 32, 64);
    float linv[4];
#pragma unroll
    for (int r = 0; r < 4; ++r) linv[r] = 1.0f / __shfl(Lf, g * 4 + r, 64);
#pragma unroll
    for (int nd = 0; nd < 4; ++nd)
#pragma unroll
      for (int r = 0; r < 4; ++r) {
        int t = qb * 64 + wave * 16 + g * 4 + r;
        int dcol = h * 64 + nd * 16 + ln;
        O[((size_t)(b * Tc + t)) * Dc + dcol] = f2bf(accO[nd][r] * linv[r]);
      }
  }
#undef STAGE
}

// -----------------------------------------------------------------------------
extern "C" void kernel_launch(void* const* d_in, const int* in_sizes, int n_in,
                              void* d_out, int out_size, void* d_ws, size_t ws_size,
                              hipStream_t stream) {
  const float* q  = (const float*)d_in[0];
  const float* k  = (const float*)d_in[1];
  const float* v  = (const float*)d_in[2];
  // d_in[3] = alibi_bias [H,T,T] — intentionally unused (computed on the fly)
  const float* wq = (const float*)d_in[4];
  const float* wk = (const float*)d_in[5];
  const float* wv = (const float*)d_in[6];
  const float* wo = (const float*)d_in[7];
  const float* bo = (const float*)d_in[8];

  char* ws = (char*)d_ws;
  const size_t MB = 1024 * 1024;
  u16* Xq = (u16*)(ws + 0 * MB);    // [4096,1024] bf16
  u16* Xk = (u16*)(ws + 8 * MB);
  u16* Xv = (u16*)(ws + 16 * MB);
  u16* Wq = (u16*)(ws + 24 * MB);   // [1024,1024] bf16
  u16* Wk = (u16*)(ws + 26 * MB);
  u16* Wv = (u16*)(ws + 28 * MB);
  u16* Wo = (u16*)(ws + 30 * MB);
  u16* Qh = (u16*)(ws + 32 * MB);   // [B,H,T,DK] bf16
  u16* Kh = (u16*)(ws + 40 * MB);   // [B,H,T,DK]
  u16* VT = (u16*)(ws + 48 * MB);   // [B,H,DK,T]
  u16* Ob = (u16*)(ws + 56 * MB);   // [B,T,D]
  float* out = (float*)d_out;

  // f32 -> bf16 (single dispatch, packed grid: X's + W's, no empty blocks)
  conv_kernel<<<dim3(4096, 1, 4), 256, 0, stream>>>(q, k, v, wq, wk, wv, wo,
                                                    Xq, Xk, Xv, Wq, Wk, Wv, Wo);
  // fused Q/K/V projections (768 blocks = 3/CU, BM=128, XCD swizzle) — R11 best
  gemm_proj<<<dim3(768), 256, 0, stream>>>(Xq, Xk, Xv, Wq, Wk, Wv, Qh, Kh, VT);
  // attention (paired q-tiles + XCD swizzle: 512 blocks, balanced)
  flash_attn<<<dim3(512), 256, 0, stream>>>(Qh, Kh, VT, Ob);
  // output projection + bias -> f32 d_out (512 blocks, XCD swizzle)
  gemm_out<<<dim3(512), 256, 0, stream>>>(Ob, Wo, out, bo);
}